// Round 10
// baseline (774.088 us; speedup 1.0000x reference)
//
#include <hip/hip_runtime.h>
#include <math.h>

// SpikingSelfAttention: B=8 S=1024 E=768 H=12 D=64 T=10
constexpr int B_ = 8, S_ = 1024, E_ = 768, H_ = 12, D_ = 64, T_ = 10;
constexpr int N_ = B_ * S_;        // 8192
constexpr int NE_ = N_ * E_;       // 6291456
constexpr int WE_ = E_ * E_;       // 589824

typedef __attribute__((ext_vector_type(8))) short bf16x8;
typedef __attribute__((ext_vector_type(4))) float f32x4;

#define MFMA16(a,b,c) __builtin_amdgcn_mfma_f32_16x16x32_bf16(a,b,c,0,0,0)

__device__ __forceinline__ float sigm(float z){ return 1.f/(1.f+__expf(-z)); }
__device__ __forceinline__ unsigned short f2bf(float f){
    unsigned int u = __float_as_uint(f);
    u += 0x7FFFu + ((u>>16)&1u);           // RN-even
    return (unsigned short)(u>>16);
}
__device__ __forceinline__ float bf2f(unsigned short h){
    return __uint_as_float(((unsigned int)h)<<16);
}
__device__ __forceinline__ void gl16(const void* g, void* l){
    __builtin_amdgcn_global_load_lds((const __attribute__((address_space(1))) unsigned int*)g,
                                     (__attribute__((address_space(3))) unsigned int*)l, 16, 0, 0);
}

// ---------------------------------------------------------------------------
// encode: enc[t][n][e] = bf16(sigmoid(100*clip(x,0,1) - 10t)), 8 elems/thread
__global__ __launch_bounds__(256) void encode_k(const float* __restrict__ x,
                                                unsigned short* __restrict__ enc){
    const int i = blockIdx.x*256 + threadIdx.x;
    const float4 a = ((const float4*)x)[2*i];
    const float4 b = ((const float4*)x)[2*i+1];
    float p[8] = {a.x,a.y,a.z,a.w,b.x,b.y,b.z,b.w};
#pragma unroll
    for (int e=0;e<8;++e) p[e] = 100.f*fminf(fmaxf(p[e],0.f),1.f);
#pragma unroll
    for (int t=0;t<T_;++t){
        unsigned int w[4];
#pragma unroll
        for (int e=0;e<4;++e){
            unsigned short u0 = f2bf(sigm(p[2*e]   - 10.f*(float)t));
            unsigned short u1 = f2bf(sigm(p[2*e+1] - 10.f*(float)t));
            w[e] = (unsigned int)u0 | ((unsigned int)u1<<16);
        }
        ((uint4*)(enc + (long)t*NE_))[i] = make_uint4(w[0],w[1],w[2],w[3]);
    }
}

// ---------------------------------------------------------------------------
// split weights into hi/lo bf16: whi[z], wlo[z], z in {q,k,v,o}
__global__ __launch_bounds__(256) void wsplit_k(const float* __restrict__ Wq, const float* __restrict__ Wk,
        const float* __restrict__ Wv, const float* __restrict__ Wo,
        unsigned short* __restrict__ whi, unsigned short* __restrict__ wlo){
    int gi = blockIdx.x*256 + threadIdx.x;
    int z = gi / (WE_/8);
    int r = gi % (WE_/8);
    const float* W = z==0?Wq : z==1?Wk : z==2?Wv : Wo;
    const float4 a = ((const float4*)W)[2*r];
    const float4 b = ((const float4*)W)[2*r+1];
    float f[8]={a.x,a.y,a.z,a.w,b.x,b.y,b.z,b.w};
    unsigned int h[4], l[4];
#pragma unroll
    for (int e=0;e<4;++e){
        unsigned short h0=f2bf(f[2*e]),   l0=f2bf(f[2*e]  -bf2f(h0));
        unsigned short h1=f2bf(f[2*e+1]), l1=f2bf(f[2*e+1]-bf2f(h1));
        h[e] = (unsigned)h0 | ((unsigned)h1<<16);
        l[e] = (unsigned)l0 | ((unsigned)l1<<16);
    }
    ((uint4*)(whi + (long)z*WE_))[r] = make_uint4(h[0],h[1],h[2],h[3]);
    ((uint4*)(wlo + (long)z*WE_))[r] = make_uint4(l[0],l[1],l[2],l[3]);
}

// ---------------------------------------------------------------------------
// fused QKV GEMM (MFMA, W plain bf16) + in-register LIF over 10 timesteps.
// r9 structure (single-buffered, plain __syncthreads, natural grid) +
// r7's 2-timestep fusion: per window stage enc[2tp],enc[2tp+1],W (10 loads),
// 32 MFMA. LDS 40KB -> 4 blocks/CU; VGPR target 128 (r7 measured spill-free).
__global__ __launch_bounds__(256,4) void qkv_k(const unsigned short* __restrict__ enc,
        const unsigned short* __restrict__ whi,
        const float* __restrict__ bq, const float* __restrict__ bk, const float* __restrict__ bv,
        float* __restrict__ Qf, float* __restrict__ Kf, float* __restrict__ Vf){
    const int z = blockIdx.z;
    const unsigned short* Wh = whi + (long)z*WE_;
    const float* bias = z==0?bq : z==1?bk : bv;
    float* Out = z==0?Qf : z==1?Kf : Vf;
    const int row0 = blockIdx.x*128, col0 = blockIdx.y*64;

    __shared__ unsigned short Ab[2][128*64];   // [t-parity] 2 x 16KB
    __shared__ unsigned short Bh[64*64];       // 8KB

    const int tid = threadIdx.x, lane = tid&63, wid = tid>>6;
    const int l15 = lane&15, l4 = lane>>4, l7 = lane&7;
    const int wr = wid>>1, wc = wid&1;

    // staging source offsets (element units); LDS dest linear, source pre-inverse-swizzled
    int aSrc[4], bSrc[2];
#pragma unroll
    for (int s=0;s<4;++s){
        int idx = (wid + s*4)*64 + lane;      // [0,1024)
        int row = idx>>3, ch = idx&7;
        aSrc[s] = (row0+row)*E_ + ((ch ^ (row&7))<<3);
    }
#pragma unroll
    for (int s=0;s<2;++s){
        int idx = (wid + s*4)*64 + lane;      // [0,512)
        int row = idx>>3, ch = idx&7;
        bSrc[s] = (col0+row)*E_ + ((ch ^ (row&7))<<3);
    }

    const int aBase = (wr*64 + l15)*128;
    const int bBase = (wc*32 + l15)*128;
    const int sw[2] = { ((l4^l7)<<4), ((((4+l4))^l7)<<4) };

    f32x4 acc0[4][2], acc1[4][2];
    float vm[4][2][4] = {};     // membrane potential (registers across t)
    float qa[4][2][4] = {};     // spike accumulator
    float bn[2];
#pragma unroll
    for (int n=0;n<2;++n) bn[n] = bias[col0 + wc*32 + n*16 + l15];
    const f32x4 zero4 = {0.f,0.f,0.f,0.f};

    for (int tp=0;tp<5;++tp){
        const long tb0 = (long)(2*tp)*NE_;
        const long tb1 = tb0 + NE_;
#pragma unroll
        for (int m=0;m<4;++m)
#pragma unroll
            for (int n=0;n<2;++n){ acc0[m][n] = zero4; acc1[m][n] = zero4; }
        for (int kt=0;kt<12;++kt){
            const int k0 = kt*64;
            __syncthreads();
#pragma unroll
            for (int s=0;s<4;++s){
                gl16(enc + tb0 + aSrc[s] + k0, &Ab[0][(wid+s*4)*512]);
                gl16(enc + tb1 + aSrc[s] + k0, &Ab[1][(wid+s*4)*512]);
            }
#pragma unroll
            for (int s=0;s<2;++s)
                gl16(Wh + bSrc[s] + k0, &Bh[(wid+s*4)*512]);
            __syncthreads();
#pragma unroll
            for (int kk=0;kk<2;++kk){
                bf16x8 af0[4], af1[4], fbh[2];
#pragma unroll
                for (int m=0;m<4;++m){
                    af0[m] = *(const bf16x8*)((const char*)&Ab[0][0] + aBase + m*2048 + sw[kk]);
                    af1[m] = *(const bf16x8*)((const char*)&Ab[1][0] + aBase + m*2048 + sw[kk]);
                }
#pragma unroll
                for (int n=0;n<2;++n)
                    fbh[n] = *(const bf16x8*)((const char*)Bh + bBase + n*2048 + sw[kk]);
#pragma unroll
                for (int m=0;m<4;++m)
#pragma unroll
                    for (int n=0;n<2;++n){
                        acc0[m][n] = MFMA16(af0[m], fbh[n], acc0[m][n]);
                        acc1[m][n] = MFMA16(af1[m], fbh[n], acc1[m][n]);
                    }
            }
        }
        // LIF updates for t=2tp then t=2tp+1, registers only
#pragma unroll
        for (int m=0;m<4;++m)
#pragma unroll
            for (int n=0;n<2;++n)
#pragma unroll
                for (int j=0;j<4;++j){
                    float I0 = acc0[m][n][j] + bn[n];
                    float v = (vm[m][n][j] + I0)*0.5f;
                    float s = sigm(10.f*v - 10.f);
                    v = v*(1.f - s);
                    qa[m][n][j] += s;
                    float I1 = acc1[m][n][j] + bn[n];
                    v = (v + I1)*0.5f;
                    s = sigm(10.f*v - 10.f);
                    vm[m][n][j] = v*(1.f - s);
                    qa[m][n][j] += s;
                }
    }
#pragma unroll
    for (int m=0;m<4;++m)
#pragma unroll
        for (int n=0;n<2;++n)
#pragma unroll
            for (int j=0;j<4;++j){
                int row = row0 + wr*64 + m*16 + l4*4 + j;
                int col = col0 + wc*32 + n*16 + l15;
                Out[(long)row*E_ + col] = qa[m][n][j];
            }
}

// ---------------------------------------------------------------------------
// flash attention, hi/lo-split bf16 MFMA. Per block: 64 q-rows, one (b,h).
// Natural grid dim3(16,12,8) (best measured locality).
__global__ __launch_bounds__(256,2) void attn_k2(const float* __restrict__ Qf, const float* __restrict__ Kf,
        const float* __restrict__ Vf, unsigned short* __restrict__ atth, unsigned short* __restrict__ attl){
    const int q0 = blockIdx.x*64;
    const int h  = blockIdx.y;
    const int b  = blockIdx.z;
    const long base = ((long)b*S_)*E_ + h*64;

    __shared__ char smem[65536];
    unsigned short* Qh = (unsigned short*)(smem);
    unsigned short* Ql = (unsigned short*)(smem + 8192);
    unsigned short* Kh = (unsigned short*)(smem + 16384);
    unsigned short* Kl = (unsigned short*)(smem + 24576);
    unsigned short* Vh = (unsigned short*)(smem + 32768);  // [d][key] transposed
    unsigned short* Vl = (unsigned short*)(smem + 40960);
    unsigned short* Ph = (unsigned short*)(smem + 49152);  // [q][key]
    unsigned short* Pl = (unsigned short*)(smem + 57344);
    float* OT = (float*)(smem + 16384);                    // [64][68] reuse K/V region

    const int tid = threadIdx.x, lane = tid&63, wid = tid>>6;
    const int l15 = lane&15, l4 = lane>>4, l7 = lane&7;
    const int qrow = wid*16 + l15;

    // stage Q split (once)
    {
        int q = tid>>2, c0 = (tid&3)*2;
        const float* src = Qf + base + (long)(q0+q)*E_ + (tid&3)*16;
        float4 f0=((const float4*)src)[0], f1=((const float4*)src)[1];
        float4 f2=((const float4*)src)[2], f3=((const float4*)src)[3];
        float f[16]={f0.x,f0.y,f0.z,f0.w,f1.x,f1.y,f1.z,f1.w,f2.x,f2.y,f2.z,f2.w,f3.x,f3.y,f3.z,f3.w};
        bf16x8 vh[2], vl[2];
#pragma unroll
        for (int g=0;g<2;++g)
#pragma unroll
            for (int e=0;e<8;++e){
                unsigned short hh = f2bf(f[g*8+e]);
                vh[g][e] = (short)hh;
                vl[g][e] = (short)f2bf(f[g*8+e]-bf2f(hh));
            }
        int by0 = q*128 + (((c0  ) ^ (q&7))<<4);
        int by1 = q*128 + (((c0+1) ^ (q&7))<<4);
        *(bf16x8*)((char*)Qh + by0) = vh[0];
        *(bf16x8*)((char*)Qh + by1) = vh[1];
        *(bf16x8*)((char*)Ql + by0) = vl[0];
        *(bf16x8*)((char*)Ql + by1) = vl[1];
    }
    __syncthreads();
    bf16x8 qfh[2], qfl[2];
#pragma unroll
    for (int kk=0;kk<2;++kk){
        int off = qrow*128 + ((((kk<<2)+l4) ^ l7)<<4);
        qfh[kk] = *(const bf16x8*)((const char*)Qh + off);
        qfl[kk] = *(const bf16x8*)((const char*)Ql + off);
    }

    float mrun = -1e30f, lrun = 0.f;
    f32x4 ot[4];
    const f32x4 zero4 = {0.f,0.f,0.f,0.f};
#pragma unroll
    for (int m=0;m<4;++m) ot[m] = zero4;

    for (int kt=0;kt<16;++kt){
        const int k0 = kt*64;
        __syncthreads();
        // stage K split
        {
            int key = tid>>2, c0 = (tid&3)*2;
            const float* src = Kf + base + (long)(k0+key)*E_ + (tid&3)*16;
            float4 f0=((const float4*)src)[0], f1=((const float4*)src)[1];
            float4 f2=((const float4*)src)[2], f3=((const float4*)src)[3];
            float f[16]={f0.x,f0.y,f0.z,f0.w,f1.x,f1.y,f1.z,f1.w,f2.x,f2.y,f2.z,f2.w,f3.x,f3.y,f3.z,f3.w};
            bf16x8 vh[2], vl[2];
#pragma unroll
            for (int g=0;g<2;++g)
#pragma unroll
                for (int e=0;e<8;++e){
                    unsigned short hh = f2bf(f[g*8+e]);
                    vh[g][e] = (short)hh;
                    vl[g][e] = (short)f2bf(f[g*8+e]-bf2f(hh));
                }
            int by0 = key*128 + (((c0  ) ^ (key&7))<<4);
            int by1 = key*128 + (((c0+1) ^ (key&7))<<4);
            *(bf16x8*)((char*)Kh + by0) = vh[0];
            *(bf16x8*)((char*)Kh + by1) = vh[1];
            *(bf16x8*)((char*)Kl + by0) = vl[0];
            *(bf16x8*)((char*)Kl + by1) = vl[1];
        }
        // stage V transposed + split, packed b32 writes
#pragma unroll
        for (int rr=0;rr<2;++rr){
            int dq = (tid>>5) + rr*8;      // d-quad [0,16)
            int kp = tid&31;               // key pair
            const float* s0 = Vf + base + (long)(k0 + 2*kp)*E_ + dq*4;
            float4 va = *(const float4*)s0;
            float4 vb = *(const float4*)(s0 + E_);
            float fa[4]={va.x,va.y,va.z,va.w}, fb[4]={vb.x,vb.y,vb.z,vb.w};
#pragma unroll
            for (int dd=0;dd<4;++dd){
                int d = dq*4+dd;
                unsigned short ha=f2bf(fa[dd]), hb=f2bf(fb[dd]);
                unsigned short la=f2bf(fa[dd]-bf2f(ha)), lb=f2bf(fb[dd]-bf2f(hb));
                int byte = d*128 + ((kp<<2) ^ ((d&7)<<4));
                *(unsigned int*)((char*)Vh + byte) = (unsigned)ha | ((unsigned)hb<<16);
                *(unsigned int*)((char*)Vl + byte) = (unsigned)la | ((unsigned)lb<<16);
            }
        }
        __syncthreads();
        // S^T = K * Q^T  (3 hi/lo products)
        f32x4 st[4];
#pragma unroll
        for (int m=0;m<4;++m) st[m] = zero4;
#pragma unroll
        for (int kk=0;kk<2;++kk){
            int swo = ((((kk<<2)+l4) ^ l7)<<4);
            bf16x8 kh[4], kl2[4];
#pragma unroll
            for (int m=0;m<4;++m){
                int off = (m*16+l15)*128 + swo;
                kh[m]  = *(const bf16x8*)((const char*)Kh + off);
                kl2[m] = *(const bf16x8*)((const char*)Kl + off);
            }
#pragma unroll
            for (int m=0;m<4;++m){
                st[m] = MFMA16(kh[m],  qfh[kk], st[m]);
                st[m] = MFMA16(kh[m],  qfl[kk], st[m]);
                st[m] = MFMA16(kl2[m], qfh[kk], st[m]);
            }
        }
        // online softmax (lane's q = qrow; 4 lanes share a q via xor16/32)
        float pmax = -1e30f;
#pragma unroll
        for (int m=0;m<4;++m)
#pragma unroll
            for (int j=0;j<4;++j){ st[m][j] *= 0.125f; pmax = fmaxf(pmax, st[m][j]); }
        pmax = fmaxf(pmax, __shfl_xor(pmax,16));
        pmax = fmaxf(pmax, __shfl_xor(pmax,32));
        float mnew = fmaxf(mrun, pmax);
        float alpha = __expf(mrun - mnew);
        float p[16]; float psum = 0.f;
#pragma unroll
        for (int m=0;m<4;++m)
#pragma unroll
            for (int j=0;j<4;++j){ float e = __expf(st[m][j]-mnew); p[m*4+j]=e; psum+=e; }
        psum += __shfl_xor(psum,16);
        psum += __shfl_xor(psum,32);
        lrun = lrun*alpha + psum;
        mrun = mnew;
#pragma unroll
        for (int m=0;m<4;++m)
#pragma unroll
            for (int j=0;j<4;++j) ot[m][j] *= alpha;
        // write P^T split (wave-private rows, packed pairs)
#pragma unroll
        for (int m=0;m<4;++m)
#pragma unroll
            for (int jp=0;jp<2;++jp){
                float fx = p[m*4+jp*2], fy = p[m*4+jp*2+1];
                unsigned short hx=f2bf(fx), hy=f2bf(fy);
                unsigned short lx=f2bf(fx-bf2f(hx)), ly=f2bf(fy-bf2f(hy));
                int key = m*16 + l4*4 + jp*2;
                int byte = qrow*128 + ((key<<1) ^ (l7<<4));
                *(unsigned int*)((char*)Ph + byte) = (unsigned)hx | ((unsigned)hy<<16);
                *(unsigned int*)((char*)Pl + byte) = (unsigned)lx | ((unsigned)ly<<16);
            }
        // O^T += V^T * P^T (3 hi/lo products)
#pragma unroll
        for (int kk=0;kk<2;++kk){
            int swo = ((((kk<<2)+l4) ^ l7)<<4);
            bf16x8 pfh = *(const bf16x8*)((const char*)Ph + qrow*128 + swo);
            bf16x8 pfl = *(const bf16x8*)((const char*)Pl + qrow*128 + swo);
#pragma unroll
            for (int m=0;m<4;++m){
                int off = (m*16+l15)*128 + swo;
                bf16x8 vvh = *(const bf16x8*)((const char*)Vh + off);
                bf16x8 vvl = *(const bf16x8*)((const char*)Vl + off);
                ot[m] = MFMA16(vvh, pfh, ot[m]);
                ot[m] = MFMA16(vvh, pfl, ot[m]);
                ot[m] = MFMA16(vvl, pfh, ot[m]);
            }
        }
    }
    __syncthreads();
    // normalize + transpose via LDS, write att split bf16
    float inv = 1.f/lrun;
#pragma unroll
    for (int m=0;m<4;++m)
#pragma unroll
        for (int j=0;j<4;++j){
            int d = m*16 + l4*4 + j;
            OT[qrow*68 + d] = ot[m][j]*inv;
        }
    __syncthreads();
    {
        int q = tid>>2, d0 = (tid&3)*16;
        const float* rp = OT + q*68 + d0;
        float4 f0=((const float4*)rp)[0], f1=((const float4*)rp)[1];
        float4 f2=((const float4*)rp)[2], f3=((const float4*)rp)[3];
        float f[16]={f0.x,f0.y,f0.z,f0.w,f1.x,f1.y,f1.z,f1.w,f2.x,f2.y,f2.z,f2.w,f3.x,f3.y,f3.z,f3.w};
        bf16x8 vh[2], vl[2];
#pragma unroll
        for (int g=0;g<2;++g)
#pragma unroll
            for (int e=0;e<8;++e){
                unsigned short hh = f2bf(f[g*8+e]);
                vh[g][e] = (short)hh;
                vl[g][e] = (short)f2bf(f[g*8+e]-bf2f(hh));
            }
        long o = base + (long)(q0+q)*E_ + d0;
        *(bf16x8*)(atth + o)     = vh[0];
        *(bf16x8*)(atth + o + 8) = vh[1];
        *(bf16x8*)(attl + o)     = vl[0];
        *(bf16x8*)(attl + o + 8) = vl[1];
    }
}

// ---------------------------------------------------------------------------
// output projection GEMM (att hi/lo x Wo hi/lo, 3 products) + fresh-state spike
__global__ __launch_bounds__(256,2) void out_k(const unsigned short* __restrict__ Ah_g,
        const unsigned short* __restrict__ Al_g,
        const unsigned short* __restrict__ Wh, const unsigned short* __restrict__ Wl,
        const float* __restrict__ bias, float* __restrict__ out){
    const int row0 = blockIdx.x*128, col0 = blockIdx.y*64;
    __shared__ unsigned short Ah[128*64], Al[128*64];
    __shared__ unsigned short Bh2[64*64], Bl2[64*64];

    const int tid = threadIdx.x, lane = tid&63, wid = tid>>6;
    const int l15 = lane&15, l4 = lane>>4, l7 = lane&7;
    const int wr = wid>>1, wc = wid&1;

    int aSrc[4], bSrc[2];
#pragma unroll
    for (int s=0;s<4;++s){
        int idx = (wid + s*4)*64 + lane;
        int row = idx>>3, ch = idx&7;
        aSrc[s] = (row0+row)*E_ + ((ch ^ (row&7))<<3);
    }
#pragma unroll
    for (int s=0;s<2;++s){
        int idx = (wid + s*4)*64 + lane;
        int row = idx>>3, ch = idx&7;
        bSrc[s] = (col0+row)*E_ + ((ch ^ (row&7))<<3);
    }
    const int aBase = (wr*64 + l15)*128;
    const int bBase = (wc*32 + l15)*128;
    const int sw[2] = { ((l4^l7)<<4), ((((4+l4))^l7)<<4) };

    f32x4 acc[4][2];
    const f32x4 zero4 = {0.f,0.f,0.f,0.f};
#pragma unroll
    for (int m=0;m<4;++m)
#pragma unroll
        for (int n=0;n<2;++n) acc[m][n] = zero4;

    for (int kt=0;kt<12;++kt){
        const int k0 = kt*64;
        __syncthreads();
#pragma unroll
        for (int s=0;s<4;++s){
            gl16(Ah_g + aSrc[s] + k0, &Ah[(wid+s*4)*512]);
            gl16(Al_g + aSrc[s] + k0, &Al[(wid+s*4)*512]);
        }
#pragma unroll
        for (int s=0;s<2;++s){
            gl16(Wh + bSrc[s] + k0, &Bh2[(wid+s*4)*512]);
            gl16(Wl + bSrc[s] + k0, &Bl2[(wid+s*4)*512]);
        }
        __syncthreads();
#pragma unroll
        for (int kk=0;kk<2;++kk){
            bf16x8 ah[4], al[4], fbh[2], fbl[2];
#pragma unroll
            for (int m=0;m<4;++m){
                ah[m] = *(const bf16x8*)((const char*)Ah + aBase + m*2048 + sw[kk]);
                al[m] = *(const bf16x8*)((const char*)Al + aBase + m*2048 + sw[kk]);
            }
#pragma unroll
            for (int n=0;n<2;++n){
                fbh[n] = *(const bf16x8*)((const char*)Bh2 + bBase + n*2048 + sw[kk]);
                fbl[n] = *(const bf16x8*)((const char*)Bl2 + bBase + n*2048 + sw[kk]);
            }
#pragma unroll
            for (int m=0;m<4;++m)
#pragma unroll
                for (int n=0;n<2;++n){
                    acc[m][n] = MFMA16(ah[m], fbh[n], acc[m][n]);
                    acc[m][n] = MFMA16(ah[m], fbl[n], acc[m][n]);
                    acc[m][n] = MFMA16(al[m], fbh[n], acc[m][n]);
                }
        }
    }
#pragma unroll
    for (int m=0;m<4;++m)
#pragma unroll
        for (int n=0;n<2;++n){
            float bn = bias[col0 + wc*32 + n*16 + l15];
#pragma unroll
            for (int j=0;j<4;++j){
                int row = row0 + wr*64 + m*16 + l4*4 + j;
                int col = col0 + wc*32 + n*16 + l15;
                float I = acc[m][n][j] + bn;
                out[(long)row*E_ + col] = sigm(5.f*I - 10.f);   // lif_step(0, I) spike
            }
        }
}

// ---------------------------------------------------------------------------
extern "C" void kernel_launch(void* const* d_in, const int* in_sizes, int n_in,
                              void* d_out, int out_size, void* d_ws, size_t ws_size,
                              hipStream_t stream){
    const float* x  = (const float*)d_in[0];
    const float* Wq = (const float*)d_in[1];
    const float* bq = (const float*)d_in[2];
    const float* Wk = (const float*)d_in[3];
    const float* bk = (const float*)d_in[4];
    const float* Wv = (const float*)d_in[5];
    const float* bv = (const float*)d_in[6];
    const float* Wo = (const float*)d_in[7];
    const float* bo = (const float*)d_in[8];
    float* out = (float*)d_out;

    // ws layout (~201 MiB):
    //  [0, 125829120)            enc bf16 [10][N][E]   (dead after qkv_k; att reuses)
    //  [125829120, 135266304)    whi/wlo bf16 [4][E*E]
    //  [135266304, 210763776)    Qf/Kf/Vf fp32 [N][E]
    char* ws = (char*)d_ws;
    unsigned short* enc  = (unsigned short*)ws;
    unsigned short* atth = (unsigned short*)ws;
    unsigned short* attl = (unsigned short*)(ws + (long)NE_*2);
    unsigned short* whi  = (unsigned short*)(ws + 125829120L);
    unsigned short* wlo  = whi + 4L*WE_;
    float* Qf = (float*)(ws + 135266304L);
    float* Kf = Qf + NE_;
    float* Vf = Kf + NE_;

    wsplit_k<<<dim3(4*(WE_/8)/256), 256, 0, stream>>>(Wq,Wk,Wv,Wo,whi,wlo);
    encode_k<<<dim3(NE_/8/256), 256, 0, stream>>>(x,enc);
    qkv_k<<<dim3(64,12,3), 256, 0, stream>>>(enc,whi,bq,bk,bv,Qf,Kf,Vf);
    attn_k2<<<dim3(16,12,8), 256, 0, stream>>>(Qf,Kf,Vf,atth,attl);
    out_k<<<dim3(64,12), 256, 0, stream>>>(atth,attl,whi+3L*WE_,wlo+3L*WE_,bo,out);
}

// Round 11
// 651.229 us; speedup vs baseline: 1.1887x; 1.1887x over previous
//
#include <hip/hip_runtime.h>
#include <math.h>

// SpikingSelfAttention: B=8 S=1024 E=768 H=12 D=64 T=10
constexpr int B_ = 8, S_ = 1024, E_ = 768, H_ = 12, D_ = 64, T_ = 10;
constexpr int N_ = B_ * S_;        // 8192
constexpr int NE_ = N_ * E_;       // 6291456
constexpr int WE_ = E_ * E_;       // 589824

typedef __attribute__((ext_vector_type(8))) short bf16x8;
typedef __attribute__((ext_vector_type(4))) float f32x4;

#define MFMA16(a,b,c) __builtin_amdgcn_mfma_f32_16x16x32_bf16(a,b,c,0,0,0)

__device__ __forceinline__ float sigm(float z){ return 1.f/(1.f+__expf(-z)); }
__device__ __forceinline__ unsigned short f2bf(float f){
    unsigned int u = __float_as_uint(f);
    u += 0x7FFFu + ((u>>16)&1u);           // RN-even
    return (unsigned short)(u>>16);
}
__device__ __forceinline__ float bf2f(unsigned short h){
    return __uint_as_float(((unsigned int)h)<<16);
}
__device__ __forceinline__ void gl16(const void* g, void* l){
    __builtin_amdgcn_global_load_lds((const __attribute__((address_space(1))) unsigned int*)g,
                                     (__attribute__((address_space(3))) unsigned int*)l, 16, 0, 0);
}

// ---------------------------------------------------------------------------
// encode: enc[t][n][e] = bf16(sigmoid(100*clip(x,0,1) - 10t)), 8 elems/thread
__global__ __launch_bounds__(256) void encode_k(const float* __restrict__ x,
                                                unsigned short* __restrict__ enc){
    const int i = blockIdx.x*256 + threadIdx.x;
    const float4 a = ((const float4*)x)[2*i];
    const float4 b = ((const float4*)x)[2*i+1];
    float p[8] = {a.x,a.y,a.z,a.w,b.x,b.y,b.z,b.w};
#pragma unroll
    for (int e=0;e<8;++e) p[e] = 100.f*fminf(fmaxf(p[e],0.f),1.f);
#pragma unroll
    for (int t=0;t<T_;++t){
        unsigned int w[4];
#pragma unroll
        for (int e=0;e<4;++e){
            unsigned short u0 = f2bf(sigm(p[2*e]   - 10.f*(float)t));
            unsigned short u1 = f2bf(sigm(p[2*e+1] - 10.f*(float)t));
            w[e] = (unsigned int)u0 | ((unsigned int)u1<<16);
        }
        ((uint4*)(enc + (long)t*NE_))[i] = make_uint4(w[0],w[1],w[2],w[3]);
    }
}

// ---------------------------------------------------------------------------
// split weights into hi/lo bf16: whi[z], wlo[z], z in {q,k,v,o}
__global__ __launch_bounds__(256) void wsplit_k(const float* __restrict__ Wq, const float* __restrict__ Wk,
        const float* __restrict__ Wv, const float* __restrict__ Wo,
        unsigned short* __restrict__ whi, unsigned short* __restrict__ wlo){
    int gi = blockIdx.x*256 + threadIdx.x;
    int z = gi / (WE_/8);
    int r = gi % (WE_/8);
    const float* W = z==0?Wq : z==1?Wk : z==2?Wv : Wo;
    const float4 a = ((const float4*)W)[2*r];
    const float4 b = ((const float4*)W)[2*r+1];
    float f[8]={a.x,a.y,a.z,a.w,b.x,b.y,b.z,b.w};
    unsigned int h[4], l[4];
#pragma unroll
    for (int e=0;e<4;++e){
        unsigned short h0=f2bf(f[2*e]),   l0=f2bf(f[2*e]  -bf2f(h0));
        unsigned short h1=f2bf(f[2*e+1]), l1=f2bf(f[2*e+1]-bf2f(h1));
        h[e] = (unsigned)h0 | ((unsigned)h1<<16);
        l[e] = (unsigned)l0 | ((unsigned)l1<<16);
    }
    ((uint4*)(whi + (long)z*WE_))[r] = make_uint4(h[0],h[1],h[2],h[3]);
    ((uint4*)(wlo + (long)z*WE_))[r] = make_uint4(l[0],l[1],l[2],l[3]);
}

// ---------------------------------------------------------------------------
// fused QKV GEMM (MFMA, W plain bf16) + in-register LIF over 10 timesteps.
// Single-buffered, plain __syncthreads, natural grid + 2-timestep fusion:
// per window stage enc[2tp],enc[2tp+1],W (10 loads), 32 MFMA.
// LDS 40KB; __launch_bounds__(256,2) -> VGPR ~128, no spill (r7-measured),
// occupancy 4 waves/SIMD (VGPR-limited) = 4 blocks/CU.
__global__ __launch_bounds__(256,2) void qkv_k(const unsigned short* __restrict__ enc,
        const unsigned short* __restrict__ whi,
        const float* __restrict__ bq, const float* __restrict__ bk, const float* __restrict__ bv,
        float* __restrict__ Qf, float* __restrict__ Kf, float* __restrict__ Vf){
    const int z = blockIdx.z;
    const unsigned short* Wh = whi + (long)z*WE_;
    const float* bias = z==0?bq : z==1?bk : bv;
    float* Out = z==0?Qf : z==1?Kf : Vf;
    const int row0 = blockIdx.x*128, col0 = blockIdx.y*64;

    __shared__ unsigned short Ab[2][128*64];   // [t-parity] 2 x 16KB
    __shared__ unsigned short Bh[64*64];       // 8KB

    const int tid = threadIdx.x, lane = tid&63, wid = tid>>6;
    const int l15 = lane&15, l4 = lane>>4, l7 = lane&7;
    const int wr = wid>>1, wc = wid&1;

    // staging source offsets (element units); LDS dest linear, source pre-inverse-swizzled
    int aSrc[4], bSrc[2];
#pragma unroll
    for (int s=0;s<4;++s){
        int idx = (wid + s*4)*64 + lane;      // [0,1024)
        int row = idx>>3, ch = idx&7;
        aSrc[s] = (row0+row)*E_ + ((ch ^ (row&7))<<3);
    }
#pragma unroll
    for (int s=0;s<2;++s){
        int idx = (wid + s*4)*64 + lane;      // [0,512)
        int row = idx>>3, ch = idx&7;
        bSrc[s] = (col0+row)*E_ + ((ch ^ (row&7))<<3);
    }

    const int aBase = (wr*64 + l15)*128;
    const int bBase = (wc*32 + l15)*128;
    const int sw[2] = { ((l4^l7)<<4), ((((4+l4))^l7)<<4) };

    f32x4 acc0[4][2], acc1[4][2];
    float vm[4][2][4] = {};     // membrane potential (registers across t)
    float qa[4][2][4] = {};     // spike accumulator
    float bn[2];
#pragma unroll
    for (int n=0;n<2;++n) bn[n] = bias[col0 + wc*32 + n*16 + l15];
    const f32x4 zero4 = {0.f,0.f,0.f,0.f};

    for (int tp=0;tp<5;++tp){
        const long tb0 = (long)(2*tp)*NE_;
        const long tb1 = tb0 + NE_;
#pragma unroll
        for (int m=0;m<4;++m)
#pragma unroll
            for (int n=0;n<2;++n){ acc0[m][n] = zero4; acc1[m][n] = zero4; }
        for (int kt=0;kt<12;++kt){
            const int k0 = kt*64;
            __syncthreads();
#pragma unroll
            for (int s=0;s<4;++s){
                gl16(enc + tb0 + aSrc[s] + k0, &Ab[0][(wid+s*4)*512]);
                gl16(enc + tb1 + aSrc[s] + k0, &Ab[1][(wid+s*4)*512]);
            }
#pragma unroll
            for (int s=0;s<2;++s)
                gl16(Wh + bSrc[s] + k0, &Bh[(wid+s*4)*512]);
            __syncthreads();
#pragma unroll
            for (int kk=0;kk<2;++kk){
                bf16x8 af0[4], af1[4], fbh[2];
#pragma unroll
                for (int m=0;m<4;++m){
                    af0[m] = *(const bf16x8*)((const char*)&Ab[0][0] + aBase + m*2048 + sw[kk]);
                    af1[m] = *(const bf16x8*)((const char*)&Ab[1][0] + aBase + m*2048 + sw[kk]);
                }
#pragma unroll
                for (int n=0;n<2;++n)
                    fbh[n] = *(const bf16x8*)((const char*)Bh + bBase + n*2048 + sw[kk]);
#pragma unroll
                for (int m=0;m<4;++m)
#pragma unroll
                    for (int n=0;n<2;++n){
                        acc0[m][n] = MFMA16(af0[m], fbh[n], acc0[m][n]);
                        acc1[m][n] = MFMA16(af1[m], fbh[n], acc1[m][n]);
                    }
            }
        }
        // LIF updates for t=2tp then t=2tp+1, registers only
#pragma unroll
        for (int m=0;m<4;++m)
#pragma unroll
            for (int n=0;n<2;++n)
#pragma unroll
                for (int j=0;j<4;++j){
                    float I0 = acc0[m][n][j] + bn[n];
                    float v = (vm[m][n][j] + I0)*0.5f;
                    float s = sigm(10.f*v - 10.f);
                    v = v*(1.f - s);
                    qa[m][n][j] += s;
                    float I1 = acc1[m][n][j] + bn[n];
                    v = (v + I1)*0.5f;
                    s = sigm(10.f*v - 10.f);
                    vm[m][n][j] = v*(1.f - s);
                    qa[m][n][j] += s;
                }
    }
#pragma unroll
    for (int m=0;m<4;++m)
#pragma unroll
        for (int n=0;n<2;++n)
#pragma unroll
            for (int j=0;j<4;++j){
                int row = row0 + wr*64 + m*16 + l4*4 + j;
                int col = col0 + wc*32 + n*16 + l15;
                Out[(long)row*E_ + col] = qa[m][n][j];
            }
}

// ---------------------------------------------------------------------------
// flash attention, hi/lo-split bf16 MFMA. Per block: 64 q-rows, one (b,h).
// Natural grid dim3(16,12,8) (best measured locality).
__global__ __launch_bounds__(256,2) void attn_k2(const float* __restrict__ Qf, const float* __restrict__ Kf,
        const float* __restrict__ Vf, unsigned short* __restrict__ atth, unsigned short* __restrict__ attl){
    const int q0 = blockIdx.x*64;
    const int h  = blockIdx.y;
    const int b  = blockIdx.z;
    const long base = ((long)b*S_)*E_ + h*64;

    __shared__ char smem[65536];
    unsigned short* Qh = (unsigned short*)(smem);
    unsigned short* Ql = (unsigned short*)(smem + 8192);
    unsigned short* Kh = (unsigned short*)(smem + 16384);
    unsigned short* Kl = (unsigned short*)(smem + 24576);
    unsigned short* Vh = (unsigned short*)(smem + 32768);  // [d][key] transposed
    unsigned short* Vl = (unsigned short*)(smem + 40960);
    unsigned short* Ph = (unsigned short*)(smem + 49152);  // [q][key]
    unsigned short* Pl = (unsigned short*)(smem + 57344);
    float* OT = (float*)(smem + 16384);                    // [64][68] reuse K/V region

    const int tid = threadIdx.x, lane = tid&63, wid = tid>>6;
    const int l15 = lane&15, l4 = lane>>4, l7 = lane&7;
    const int qrow = wid*16 + l15;

    // stage Q split (once)
    {
        int q = tid>>2, c0 = (tid&3)*2;
        const float* src = Qf + base + (long)(q0+q)*E_ + (tid&3)*16;
        float4 f0=((const float4*)src)[0], f1=((const float4*)src)[1];
        float4 f2=((const float4*)src)[2], f3=((const float4*)src)[3];
        float f[16]={f0.x,f0.y,f0.z,f0.w,f1.x,f1.y,f1.z,f1.w,f2.x,f2.y,f2.z,f2.w,f3.x,f3.y,f3.z,f3.w};
        bf16x8 vh[2], vl[2];
#pragma unroll
        for (int g=0;g<2;++g)
#pragma unroll
            for (int e=0;e<8;++e){
                unsigned short hh = f2bf(f[g*8+e]);
                vh[g][e] = (short)hh;
                vl[g][e] = (short)f2bf(f[g*8+e]-bf2f(hh));
            }
        int by0 = q*128 + (((c0  ) ^ (q&7))<<4);
        int by1 = q*128 + (((c0+1) ^ (q&7))<<4);
        *(bf16x8*)((char*)Qh + by0) = vh[0];
        *(bf16x8*)((char*)Qh + by1) = vh[1];
        *(bf16x8*)((char*)Ql + by0) = vl[0];
        *(bf16x8*)((char*)Ql + by1) = vl[1];
    }
    __syncthreads();
    bf16x8 qfh[2], qfl[2];
#pragma unroll
    for (int kk=0;kk<2;++kk){
        int off = qrow*128 + ((((kk<<2)+l4) ^ l7)<<4);
        qfh[kk] = *(const bf16x8*)((const char*)Qh + off);
        qfl[kk] = *(const bf16x8*)((const char*)Ql + off);
    }

    float mrun = -1e30f, lrun = 0.f;
    f32x4 ot[4];
    const f32x4 zero4 = {0.f,0.f,0.f,0.f};
#pragma unroll
    for (int m=0;m<4;++m) ot[m] = zero4;

    for (int kt=0;kt<16;++kt){
        const int k0 = kt*64;
        __syncthreads();
        // stage K split
        {
            int key = tid>>2, c0 = (tid&3)*2;
            const float* src = Kf + base + (long)(k0+key)*E_ + (tid&3)*16;
            float4 f0=((const float4*)src)[0], f1=((const float4*)src)[1];
            float4 f2=((const float4*)src)[2], f3=((const float4*)src)[3];
            float f[16]={f0.x,f0.y,f0.z,f0.w,f1.x,f1.y,f1.z,f1.w,f2.x,f2.y,f2.z,f2.w,f3.x,f3.y,f3.z,f3.w};
            bf16x8 vh[2], vl[2];
#pragma unroll
            for (int g=0;g<2;++g)
#pragma unroll
                for (int e=0;e<8;++e){
                    unsigned short hh = f2bf(f[g*8+e]);
                    vh[g][e] = (short)hh;
                    vl[g][e] = (short)f2bf(f[g*8+e]-bf2f(hh));
                }
            int by0 = key*128 + (((c0  ) ^ (key&7))<<4);
            int by1 = key*128 + (((c0+1) ^ (key&7))<<4);
            *(bf16x8*)((char*)Kh + by0) = vh[0];
            *(bf16x8*)((char*)Kh + by1) = vh[1];
            *(bf16x8*)((char*)Kl + by0) = vl[0];
            *(bf16x8*)((char*)Kl + by1) = vl[1];
        }
        // stage V transposed + split, packed b32 writes
#pragma unroll
        for (int rr=0;rr<2;++rr){
            int dq = (tid>>5) + rr*8;      // d-quad [0,16)
            int kp = tid&31;               // key pair
            const float* s0 = Vf + base + (long)(k0 + 2*kp)*E_ + dq*4;
            float4 va = *(const float4*)s0;
            float4 vb = *(const float4*)(s0 + E_);
            float fa[4]={va.x,va.y,va.z,va.w}, fb[4]={vb.x,vb.y,vb.z,vb.w};
#pragma unroll
            for (int dd=0;dd<4;++dd){
                int d = dq*4+dd;
                unsigned short ha=f2bf(fa[dd]), hb=f2bf(fb[dd]);
                unsigned short la=f2bf(fa[dd]-bf2f(ha)), lb=f2bf(fb[dd]-bf2f(hb));
                int byte = d*128 + ((kp<<2) ^ ((d&7)<<4));
                *(unsigned int*)((char*)Vh + byte) = (unsigned)ha | ((unsigned)hb<<16);
                *(unsigned int*)((char*)Vl + byte) = (unsigned)la | ((unsigned)lb<<16);
            }
        }
        __syncthreads();
        // S^T = K * Q^T  (3 hi/lo products)
        f32x4 st[4];
#pragma unroll
        for (int m=0;m<4;++m) st[m] = zero4;
#pragma unroll
        for (int kk=0;kk<2;++kk){
            int swo = ((((kk<<2)+l4) ^ l7)<<4);
            bf16x8 kh[4], kl2[4];
#pragma unroll
            for (int m=0;m<4;++m){
                int off = (m*16+l15)*128 + swo;
                kh[m]  = *(const bf16x8*)((const char*)Kh + off);
                kl2[m] = *(const bf16x8*)((const char*)Kl + off);
            }
#pragma unroll
            for (int m=0;m<4;++m){
                st[m] = MFMA16(kh[m],  qfh[kk], st[m]);
                st[m] = MFMA16(kh[m],  qfl[kk], st[m]);
                st[m] = MFMA16(kl2[m], qfh[kk], st[m]);
            }
        }
        // online softmax (lane's q = qrow; 4 lanes share a q via xor16/32)
        float pmax = -1e30f;
#pragma unroll
        for (int m=0;m<4;++m)
#pragma unroll
            for (int j=0;j<4;++j){ st[m][j] *= 0.125f; pmax = fmaxf(pmax, st[m][j]); }
        pmax = fmaxf(pmax, __shfl_xor(pmax,16));
        pmax = fmaxf(pmax, __shfl_xor(pmax,32));
        float mnew = fmaxf(mrun, pmax);
        float alpha = __expf(mrun - mnew);
        float p[16]; float psum = 0.f;
#pragma unroll
        for (int m=0;m<4;++m)
#pragma unroll
            for (int j=0;j<4;++j){ float e = __expf(st[m][j]-mnew); p[m*4+j]=e; psum+=e; }
        psum += __shfl_xor(psum,16);
        psum += __shfl_xor(psum,32);
        lrun = lrun*alpha + psum;
        mrun = mnew;
#pragma unroll
        for (int m=0;m<4;++m)
#pragma unroll
            for (int j=0;j<4;++j) ot[m][j] *= alpha;
        // write P^T split (wave-private rows, packed pairs)
#pragma unroll
        for (int m=0;m<4;++m)
#pragma unroll
            for (int jp=0;jp<2;++jp){
                float fx = p[m*4+jp*2], fy = p[m*4+jp*2+1];
                unsigned short hx=f2bf(fx), hy=f2bf(fy);
                unsigned short lx=f2bf(fx-bf2f(hx)), ly=f2bf(fy-bf2f(hy));
                int key = m*16 + l4*4 + jp*2;
                int byte = qrow*128 + ((key<<1) ^ (l7<<4));
                *(unsigned int*)((char*)Ph + byte) = (unsigned)hx | ((unsigned)hy<<16);
                *(unsigned int*)((char*)Pl + byte) = (unsigned)lx | ((unsigned)ly<<16);
            }
        // O^T += V^T * P^T (3 hi/lo products)
#pragma unroll
        for (int kk=0;kk<2;++kk){
            int swo = ((((kk<<2)+l4) ^ l7)<<4);
            bf16x8 pfh = *(const bf16x8*)((const char*)Ph + qrow*128 + swo);
            bf16x8 pfl = *(const bf16x8*)((const char*)Pl + qrow*128 + swo);
#pragma unroll
            for (int m=0;m<4;++m){
                int off = (m*16+l15)*128 + swo;
                bf16x8 vvh = *(const bf16x8*)((const char*)Vh + off);
                bf16x8 vvl = *(const bf16x8*)((const char*)Vl + off);
                ot[m] = MFMA16(vvh, pfh, ot[m]);
                ot[m] = MFMA16(vvh, pfl, ot[m]);
                ot[m] = MFMA16(vvl, pfh, ot[m]);
            }
        }
    }
    __syncthreads();
    // normalize + transpose via LDS, write att split bf16
    float inv = 1.f/lrun;
#pragma unroll
    for (int m=0;m<4;++m)
#pragma unroll
        for (int j=0;j<4;++j){
            int d = m*16 + l4*4 + j;
            OT[qrow*68 + d] = ot[m][j]*inv;
        }
    __syncthreads();
    {
        int q = tid>>2, d0 = (tid&3)*16;
        const float* rp = OT + q*68 + d0;
        float4 f0=((const float4*)rp)[0], f1=((const float4*)rp)[1];
        float4 f2=((const float4*)rp)[2], f3=((const float4*)rp)[3];
        float f[16]={f0.x,f0.y,f0.z,f0.w,f1.x,f1.y,f1.z,f1.w,f2.x,f2.y,f2.z,f2.w,f3.x,f3.y,f3.z,f3.w};
        bf16x8 vh[2], vl[2];
#pragma unroll
        for (int g=0;g<2;++g)
#pragma unroll
            for (int e=0;e<8;++e){
                unsigned short hh = f2bf(f[g*8+e]);
                vh[g][e] = (short)hh;
                vl[g][e] = (short)f2bf(f[g*8+e]-bf2f(hh));
            }
        long o = base + (long)(q0+q)*E_ + d0;
        *(bf16x8*)(atth + o)     = vh[0];
        *(bf16x8*)(atth + o + 8) = vh[1];
        *(bf16x8*)(attl + o)     = vl[0];
        *(bf16x8*)(attl + o + 8) = vl[1];
    }
}

// ---------------------------------------------------------------------------
// output projection GEMM (att hi/lo x Wo hi/lo, 3 products) + fresh-state spike
__global__ __launch_bounds__(256,2) void out_k(const unsigned short* __restrict__ Ah_g,
        const unsigned short* __restrict__ Al_g,
        const unsigned short* __restrict__ Wh, const unsigned short* __restrict__ Wl,
        const float* __restrict__ bias, float* __restrict__ out){
    const int row0 = blockIdx.x*128, col0 = blockIdx.y*64;
    __shared__ unsigned short Ah[128*64], Al[128*64];
    __shared__ unsigned short Bh2[64*64], Bl2[64*64];

    const int tid = threadIdx.x, lane = tid&63, wid = tid>>6;
    const int l15 = lane&15, l4 = lane>>4, l7 = lane&7;
    const int wr = wid>>1, wc = wid&1;

    int aSrc[4], bSrc[2];
#pragma unroll
    for (int s=0;s<4;++s){
        int idx = (wid + s*4)*64 + lane;
        int row = idx>>3, ch = idx&7;
        aSrc[s] = (row0+row)*E_ + ((ch ^ (row&7))<<3);
    }
#pragma unroll
    for (int s=0;s<2;++s){
        int idx = (wid + s*4)*64 + lane;
        int row = idx>>3, ch = idx&7;
        bSrc[s] = (col0+row)*E_ + ((ch ^ (row&7))<<3);
    }
    const int aBase = (wr*64 + l15)*128;
    const int bBase = (wc*32 + l15)*128;
    const int sw[2] = { ((l4^l7)<<4), ((((4+l4))^l7)<<4) };

    f32x4 acc[4][2];
    const f32x4 zero4 = {0.f,0.f,0.f,0.f};
#pragma unroll
    for (int m=0;m<4;++m)
#pragma unroll
        for (int n=0;n<2;++n) acc[m][n] = zero4;

    for (int kt=0;kt<12;++kt){
        const int k0 = kt*64;
        __syncthreads();
#pragma unroll
        for (int s=0;s<4;++s){
            gl16(Ah_g + aSrc[s] + k0, &Ah[(wid+s*4)*512]);
            gl16(Al_g + aSrc[s] + k0, &Al[(wid+s*4)*512]);
        }
#pragma unroll
        for (int s=0;s<2;++s){
            gl16(Wh + bSrc[s] + k0, &Bh2[(wid+s*4)*512]);
            gl16(Wl + bSrc[s] + k0, &Bl2[(wid+s*4)*512]);
        }
        __syncthreads();
#pragma unroll
        for (int kk=0;kk<2;++kk){
            bf16x8 ah[4], al[4], fbh[2], fbl[2];
#pragma unroll
            for (int m=0;m<4;++m){
                ah[m] = *(const bf16x8*)((const char*)Ah + aBase + m*2048 + sw[kk]);
                al[m] = *(const bf16x8*)((const char*)Al + aBase + m*2048 + sw[kk]);
            }
#pragma unroll
            for (int n=0;n<2;++n){
                fbh[n] = *(const bf16x8*)((const char*)Bh2 + bBase + n*2048 + sw[kk]);
                fbl[n] = *(const bf16x8*)((const char*)Bl2 + bBase + n*2048 + sw[kk]);
            }
#pragma unroll
            for (int m=0;m<4;++m)
#pragma unroll
                for (int n=0;n<2;++n){
                    acc[m][n] = MFMA16(ah[m], fbh[n], acc[m][n]);
                    acc[m][n] = MFMA16(ah[m], fbl[n], acc[m][n]);
                    acc[m][n] = MFMA16(al[m], fbh[n], acc[m][n]);
                }
        }
    }
#pragma unroll
    for (int m=0;m<4;++m)
#pragma unroll
        for (int n=0;n<2;++n){
            float bn = bias[col0 + wc*32 + n*16 + l15];
#pragma unroll
            for (int j=0;j<4;++j){
                int row = row0 + wr*64 + m*16 + l4*4 + j;
                int col = col0 + wc*32 + n*16 + l15;
                float I = acc[m][n][j] + bn;
                out[(long)row*E_ + col] = sigm(5.f*I - 10.f);   // lif_step(0, I) spike
            }
        }
}

// ---------------------------------------------------------------------------
extern "C" void kernel_launch(void* const* d_in, const int* in_sizes, int n_in,
                              void* d_out, int out_size, void* d_ws, size_t ws_size,
                              hipStream_t stream){
    const float* x  = (const float*)d_in[0];
    const float* Wq = (const float*)d_in[1];
    const float* bq = (const float*)d_in[2];
    const float* Wk = (const float*)d_in[3];
    const float* bk = (const float*)d_in[4];
    const float* Wv = (const float*)d_in[5];
    const float* bv = (const float*)d_in[6];
    const float* Wo = (const float*)d_in[7];
    const float* bo = (const float*)d_in[8];
    float* out = (float*)d_out;

    // ws layout (~201 MiB):
    //  [0, 125829120)            enc bf16 [10][N][E]   (dead after qkv_k; att reuses)
    //  [125829120, 135266304)    whi/wlo bf16 [4][E*E]
    //  [135266304, 210763776)    Qf/Kf/Vf fp32 [N][E]
    char* ws = (char*)d_ws;
    unsigned short* enc  = (unsigned short*)ws;
    unsigned short* atth = (unsigned short*)ws;
    unsigned short* attl = (unsigned short*)(ws + (long)NE_*2);
    unsigned short* whi  = (unsigned short*)(ws + 125829120L);
    unsigned short* wlo  = whi + 4L*WE_;
    float* Qf = (float*)(ws + 135266304L);
    float* Kf = Qf + NE_;
    float* Vf = Kf + NE_;

    wsplit_k<<<dim3(4*(WE_/8)/256), 256, 0, stream>>>(Wq,Wk,Wv,Wo,whi,wlo);
    encode_k<<<dim3(NE_/8/256), 256, 0, stream>>>(x,enc);
    qkv_k<<<dim3(64,12,3), 256, 0, stream>>>(enc,whi,bq,bk,bv,Qf,Kf,Vf);
    attn_k2<<<dim3(16,12,8), 256, 0, stream>>>(Qf,Kf,Vf,atth,attl);
    out_k<<<dim3(64,12), 256, 0, stream>>>(atth,attl,whi+3L*WE_,wlo+3L*WE_,bo,out);
}

// Round 12
// 605.267 us; speedup vs baseline: 1.2789x; 1.0759x over previous
//
#include <hip/hip_runtime.h>
#include <math.h>

// SpikingSelfAttention: B=8 S=1024 E=768 H=12 D=64 T=10
constexpr int B_ = 8, S_ = 1024, E_ = 768, H_ = 12, D_ = 64, T_ = 10;
constexpr int N_ = B_ * S_;        // 8192
constexpr int NE_ = N_ * E_;       // 6291456
constexpr int WE_ = E_ * E_;       // 589824

typedef __attribute__((ext_vector_type(8))) short bf16x8;
typedef __attribute__((ext_vector_type(4))) float f32x4;

#define MFMA16(a,b,c) __builtin_amdgcn_mfma_f32_16x16x32_bf16(a,b,c,0,0,0)

__device__ __forceinline__ float sigm(float z){ return 1.f/(1.f+__expf(-z)); }
__device__ __forceinline__ unsigned short f2bf(float f){
    unsigned int u = __float_as_uint(f);
    u += 0x7FFFu + ((u>>16)&1u);           // RN-even
    return (unsigned short)(u>>16);
}
__device__ __forceinline__ float bf2f(unsigned short h){
    return __uint_as_float(((unsigned int)h)<<16);
}
__device__ __forceinline__ void gl16(const void* g, void* l){
    __builtin_amdgcn_global_load_lds((const __attribute__((address_space(1))) unsigned int*)g,
                                     (__attribute__((address_space(3))) unsigned int*)l, 16, 0, 0);
}

// ---------------------------------------------------------------------------
// encode: enc[t][n][e] = bf16(sigmoid(100*clip(x,0,1) - 10t)), 8 elems/thread
__global__ __launch_bounds__(256) void encode_k(const float* __restrict__ x,
                                                unsigned short* __restrict__ enc){
    const int i = blockIdx.x*256 + threadIdx.x;
    const float4 a = ((const float4*)x)[2*i];
    const float4 b = ((const float4*)x)[2*i+1];
    float p[8] = {a.x,a.y,a.z,a.w,b.x,b.y,b.z,b.w};
#pragma unroll
    for (int e=0;e<8;++e) p[e] = 100.f*fminf(fmaxf(p[e],0.f),1.f);
#pragma unroll
    for (int t=0;t<T_;++t){
        unsigned int w[4];
#pragma unroll
        for (int e=0;e<4;++e){
            unsigned short u0 = f2bf(sigm(p[2*e]   - 10.f*(float)t));
            unsigned short u1 = f2bf(sigm(p[2*e+1] - 10.f*(float)t));
            w[e] = (unsigned int)u0 | ((unsigned int)u1<<16);
        }
        ((uint4*)(enc + (long)t*NE_))[i] = make_uint4(w[0],w[1],w[2],w[3]);
    }
}

// ---------------------------------------------------------------------------
// split weights into hi/lo bf16: whi[z], wlo[z], z in {q,k,v,o}
__global__ __launch_bounds__(256) void wsplit_k(const float* __restrict__ Wq, const float* __restrict__ Wk,
        const float* __restrict__ Wv, const float* __restrict__ Wo,
        unsigned short* __restrict__ whi, unsigned short* __restrict__ wlo){
    int gi = blockIdx.x*256 + threadIdx.x;
    int z = gi / (WE_/8);
    int r = gi % (WE_/8);
    const float* W = z==0?Wq : z==1?Wk : z==2?Wv : Wo;
    const float4 a = ((const float4*)W)[2*r];
    const float4 b = ((const float4*)W)[2*r+1];
    float f[8]={a.x,a.y,a.z,a.w,b.x,b.y,b.z,b.w};
    unsigned int h[4], l[4];
#pragma unroll
    for (int e=0;e<4;++e){
        unsigned short h0=f2bf(f[2*e]),   l0=f2bf(f[2*e]  -bf2f(h0));
        unsigned short h1=f2bf(f[2*e+1]), l1=f2bf(f[2*e+1]-bf2f(h1));
        h[e] = (unsigned)h0 | ((unsigned)h1<<16);
        l[e] = (unsigned)l0 | ((unsigned)l1<<16);
    }
    ((uint4*)(whi + (long)z*WE_))[r] = make_uint4(h[0],h[1],h[2],h[3]);
    ((uint4*)(wlo + (long)z*WE_))[r] = make_uint4(l[0],l[1],l[2],l[3]);
}

// ---------------------------------------------------------------------------
// fused QKV GEMM (MFMA, W plain bf16) + in-register LIF over 10 timesteps.
// BEST MEASURED CONFIG (r9, 415us): tile 128x64, 4 waves (2x2),
// single-buffered 24KB LDS, plain __syncthreads, natural grid dim3(64,12,3).
// High occupancy (VGPR ~84, 6 blocks/CU theoretical) does the latency
// hiding — every explicit pipeline/tile variant (r3-r8, r11) measured worse.
__global__ __launch_bounds__(256,2) void qkv_k(const unsigned short* __restrict__ enc,
        const unsigned short* __restrict__ whi,
        const float* __restrict__ bq, const float* __restrict__ bk, const float* __restrict__ bv,
        float* __restrict__ Qf, float* __restrict__ Kf, float* __restrict__ Vf){
    const int z = blockIdx.z;
    const unsigned short* Wh = whi + (long)z*WE_;
    const float* bias = z==0?bq : z==1?bk : bv;
    float* Out = z==0?Qf : z==1?Kf : Vf;
    const int row0 = blockIdx.x*128, col0 = blockIdx.y*64;

    __shared__ unsigned short Ab[128*64];   // 16KB
    __shared__ unsigned short Bh[64*64];    // 8KB

    const int tid = threadIdx.x, lane = tid&63, wid = tid>>6;
    const int l15 = lane&15, l4 = lane>>4, l7 = lane&7;
    const int wr = wid>>1, wc = wid&1;

    // staging source offsets (element units); LDS dest linear, source pre-inverse-swizzled
    int aSrc[4], bSrc[2];
#pragma unroll
    for (int s=0;s<4;++s){
        int idx = (wid + s*4)*64 + lane;      // [0,1024)
        int row = idx>>3, ch = idx&7;
        aSrc[s] = (row0+row)*E_ + ((ch ^ (row&7))<<3);
    }
#pragma unroll
    for (int s=0;s<2;++s){
        int idx = (wid + s*4)*64 + lane;      // [0,512)
        int row = idx>>3, ch = idx&7;
        bSrc[s] = (col0+row)*E_ + ((ch ^ (row&7))<<3);
    }

    const int aBase = (wr*64 + l15)*128;
    const int bBase = (wc*32 + l15)*128;
    const int sw[2] = { ((l4^l7)<<4), ((((4+l4))^l7)<<4) };

    f32x4 acc[4][2];
    float vm[4][2][4] = {};     // membrane potential (registers across t)
    float qa[4][2][4] = {};     // spike accumulator
    float bn[2];
#pragma unroll
    for (int n=0;n<2;++n) bn[n] = bias[col0 + wc*32 + n*16 + l15];
    const f32x4 zero4 = {0.f,0.f,0.f,0.f};

    for (int t=0;t<T_;++t){
        const long tb = (long)t*NE_;
#pragma unroll
        for (int m=0;m<4;++m)
#pragma unroll
            for (int n=0;n<2;++n) acc[m][n] = zero4;
        for (int kt=0;kt<12;++kt){
            const int k0 = kt*64;
            __syncthreads();
#pragma unroll
            for (int s=0;s<4;++s)
                gl16(enc + tb + aSrc[s] + k0, &Ab[(wid+s*4)*512]);
#pragma unroll
            for (int s=0;s<2;++s)
                gl16(Wh + bSrc[s] + k0, &Bh[(wid+s*4)*512]);
            __syncthreads();
#pragma unroll
            for (int kk=0;kk<2;++kk){
                bf16x8 af[4], fbh[2];
#pragma unroll
                for (int m=0;m<4;++m)
                    af[m] = *(const bf16x8*)((const char*)Ab + aBase + m*2048 + sw[kk]);
#pragma unroll
                for (int n=0;n<2;++n)
                    fbh[n] = *(const bf16x8*)((const char*)Bh + bBase + n*2048 + sw[kk]);
#pragma unroll
                for (int m=0;m<4;++m)
#pragma unroll
                    for (int n=0;n<2;++n)
                        acc[m][n] = MFMA16(af[m], fbh[n], acc[m][n]);
            }
        }
        // LIF update, registers only (no barrier needed)
#pragma unroll
        for (int m=0;m<4;++m)
#pragma unroll
            for (int n=0;n<2;++n)
#pragma unroll
                for (int j=0;j<4;++j){
                    float I = acc[m][n][j] + bn[n];
                    float v = (vm[m][n][j] + I)*0.5f;
                    float s = sigm(10.f*v - 10.f);
                    vm[m][n][j] = v*(1.f - s);
                    qa[m][n][j] += s;
                }
    }
#pragma unroll
    for (int m=0;m<4;++m)
#pragma unroll
        for (int n=0;n<2;++n)
#pragma unroll
            for (int j=0;j<4;++j){
                int row = row0 + wr*64 + m*16 + l4*4 + j;
                int col = col0 + wc*32 + n*16 + l15;
                Out[(long)row*E_ + col] = qa[m][n][j];
            }
}

// ---------------------------------------------------------------------------
// flash attention, hi/lo-split bf16 MFMA. Per block: 64 q-rows, one (b,h).
// Natural grid dim3(16,12,8) (best measured locality). 3 products kept:
// score noise risks softmax tie-flips at O(100)-scale scores.
__global__ __launch_bounds__(256,2) void attn_k2(const float* __restrict__ Qf, const float* __restrict__ Kf,
        const float* __restrict__ Vf, unsigned short* __restrict__ atth, unsigned short* __restrict__ attl){
    const int q0 = blockIdx.x*64;
    const int h  = blockIdx.y;
    const int b  = blockIdx.z;
    const long base = ((long)b*S_)*E_ + h*64;

    __shared__ char smem[65536];
    unsigned short* Qh = (unsigned short*)(smem);
    unsigned short* Ql = (unsigned short*)(smem + 8192);
    unsigned short* Kh = (unsigned short*)(smem + 16384);
    unsigned short* Kl = (unsigned short*)(smem + 24576);
    unsigned short* Vh = (unsigned short*)(smem + 32768);  // [d][key] transposed
    unsigned short* Vl = (unsigned short*)(smem + 40960);
    unsigned short* Ph = (unsigned short*)(smem + 49152);  // [q][key]
    unsigned short* Pl = (unsigned short*)(smem + 57344);
    float* OT = (float*)(smem + 16384);                    // [64][68] reuse K/V region

    const int tid = threadIdx.x, lane = tid&63, wid = tid>>6;
    const int l15 = lane&15, l4 = lane>>4, l7 = lane&7;
    const int qrow = wid*16 + l15;

    // stage Q split (once)
    {
        int q = tid>>2, c0 = (tid&3)*2;
        const float* src = Qf + base + (long)(q0+q)*E_ + (tid&3)*16;
        float4 f0=((const float4*)src)[0], f1=((const float4*)src)[1];
        float4 f2=((const float4*)src)[2], f3=((const float4*)src)[3];
        float f[16]={f0.x,f0.y,f0.z,f0.w,f1.x,f1.y,f1.z,f1.w,f2.x,f2.y,f2.z,f2.w,f3.x,f3.y,f3.z,f3.w};
        bf16x8 vh[2], vl[2];
#pragma unroll
        for (int g=0;g<2;++g)
#pragma unroll
            for (int e=0;e<8;++e){
                unsigned short hh = f2bf(f[g*8+e]);
                vh[g][e] = (short)hh;
                vl[g][e] = (short)f2bf(f[g*8+e]-bf2f(hh));
            }
        int by0 = q*128 + (((c0  ) ^ (q&7))<<4);
        int by1 = q*128 + (((c0+1) ^ (q&7))<<4);
        *(bf16x8*)((char*)Qh + by0) = vh[0];
        *(bf16x8*)((char*)Qh + by1) = vh[1];
        *(bf16x8*)((char*)Ql + by0) = vl[0];
        *(bf16x8*)((char*)Ql + by1) = vl[1];
    }
    __syncthreads();
    bf16x8 qfh[2], qfl[2];
#pragma unroll
    for (int kk=0;kk<2;++kk){
        int off = qrow*128 + ((((kk<<2)+l4) ^ l7)<<4);
        qfh[kk] = *(const bf16x8*)((const char*)Qh + off);
        qfl[kk] = *(const bf16x8*)((const char*)Ql + off);
    }

    float mrun = -1e30f, lrun = 0.f;
    f32x4 ot[4];
    const f32x4 zero4 = {0.f,0.f,0.f,0.f};
#pragma unroll
    for (int m=0;m<4;++m) ot[m] = zero4;

    for (int kt=0;kt<16;++kt){
        const int k0 = kt*64;
        __syncthreads();
        // stage K split
        {
            int key = tid>>2, c0 = (tid&3)*2;
            const float* src = Kf + base + (long)(k0+key)*E_ + (tid&3)*16;
            float4 f0=((const float4*)src)[0], f1=((const float4*)src)[1];
            float4 f2=((const float4*)src)[2], f3=((const float4*)src)[3];
            float f[16]={f0.x,f0.y,f0.z,f0.w,f1.x,f1.y,f1.z,f1.w,f2.x,f2.y,f2.z,f2.w,f3.x,f3.y,f3.z,f3.w};
            bf16x8 vh[2], vl[2];
#pragma unroll
            for (int g=0;g<2;++g)
#pragma unroll
                for (int e=0;e<8;++e){
                    unsigned short hh = f2bf(f[g*8+e]);
                    vh[g][e] = (short)hh;
                    vl[g][e] = (short)f2bf(f[g*8+e]-bf2f(hh));
                }
            int by0 = key*128 + (((c0  ) ^ (key&7))<<4);
            int by1 = key*128 + (((c0+1) ^ (key&7))<<4);
            *(bf16x8*)((char*)Kh + by0) = vh[0];
            *(bf16x8*)((char*)Kh + by1) = vh[1];
            *(bf16x8*)((char*)Kl + by0) = vl[0];
            *(bf16x8*)((char*)Kl + by1) = vl[1];
        }
        // stage V transposed + split, packed b32 writes
#pragma unroll
        for (int rr=0;rr<2;++rr){
            int dq = (tid>>5) + rr*8;      // d-quad [0,16)
            int kp = tid&31;               // key pair
            const float* s0 = Vf + base + (long)(k0 + 2*kp)*E_ + dq*4;
            float4 va = *(const float4*)s0;
            float4 vb = *(const float4*)(s0 + E_);
            float fa[4]={va.x,va.y,va.z,va.w}, fb[4]={vb.x,vb.y,vb.z,vb.w};
#pragma unroll
            for (int dd=0;dd<4;++dd){
                int d = dq*4+dd;
                unsigned short ha=f2bf(fa[dd]), hb=f2bf(fb[dd]);
                unsigned short la=f2bf(fa[dd]-bf2f(ha)), lb=f2bf(fb[dd]-bf2f(hb));
                int byte = d*128 + ((kp<<2) ^ ((d&7)<<4));
                *(unsigned int*)((char*)Vh + byte) = (unsigned)ha | ((unsigned)hb<<16);
                *(unsigned int*)((char*)Vl + byte) = (unsigned)la | ((unsigned)lb<<16);
            }
        }
        __syncthreads();
        // S^T = K * Q^T  (3 hi/lo products)
        f32x4 st[4];
#pragma unroll
        for (int m=0;m<4;++m) st[m] = zero4;
#pragma unroll
        for (int kk=0;kk<2;++kk){
            int swo = ((((kk<<2)+l4) ^ l7)<<4);
            bf16x8 kh[4], kl2[4];
#pragma unroll
            for (int m=0;m<4;++m){
                int off = (m*16+l15)*128 + swo;
                kh[m]  = *(const bf16x8*)((const char*)Kh + off);
                kl2[m] = *(const bf16x8*)((const char*)Kl + off);
            }
#pragma unroll
            for (int m=0;m<4;++m){
                st[m] = MFMA16(kh[m],  qfh[kk], st[m]);
                st[m] = MFMA16(kh[m],  qfl[kk], st[m]);
                st[m] = MFMA16(kl2[m], qfh[kk], st[m]);
            }
        }
        // online softmax (lane's q = qrow; 4 lanes share a q via xor16/32)
        float pmax = -1e30f;
#pragma unroll
        for (int m=0;m<4;++m)
#pragma unroll
            for (int j=0;j<4;++j){ st[m][j] *= 0.125f; pmax = fmaxf(pmax, st[m][j]); }
        pmax = fmaxf(pmax, __shfl_xor(pmax,16));
        pmax = fmaxf(pmax, __shfl_xor(pmax,32));
        float mnew = fmaxf(mrun, pmax);
        float alpha = __expf(mrun - mnew);
        float p[16]; float psum = 0.f;
#pragma unroll
        for (int m=0;m<4;++m)
#pragma unroll
            for (int j=0;j<4;++j){ float e = __expf(st[m][j]-mnew); p[m*4+j]=e; psum+=e; }
        psum += __shfl_xor(psum,16);
        psum += __shfl_xor(psum,32);
        lrun = lrun*alpha + psum;
        mrun = mnew;
#pragma unroll
        for (int m=0;m<4;++m)
#pragma unroll
            for (int j=0;j<4;++j) ot[m][j] *= alpha;
        // write P^T split (wave-private rows, packed pairs)
#pragma unroll
        for (int m=0;m<4;++m)
#pragma unroll
            for (int jp=0;jp<2;++jp){
                float fx = p[m*4+jp*2], fy = p[m*4+jp*2+1];
                unsigned short hx=f2bf(fx), hy=f2bf(fy);
                unsigned short lx=f2bf(fx-bf2f(hx)), ly=f2bf(fy-bf2f(hy));
                int key = m*16 + l4*4 + jp*2;
                int byte = qrow*128 + ((key<<1) ^ (l7<<4));
                *(unsigned int*)((char*)Ph + byte) = (unsigned)hx | ((unsigned)hy<<16);
                *(unsigned int*)((char*)Pl + byte) = (unsigned)lx | ((unsigned)ly<<16);
            }
        // O^T += V^T * P^T (3 hi/lo products)
#pragma unroll
        for (int kk=0;kk<2;++kk){
            int swo = ((((kk<<2)+l4) ^ l7)<<4);
            bf16x8 pfh = *(const bf16x8*)((const char*)Ph + qrow*128 + swo);
            bf16x8 pfl = *(const bf16x8*)((const char*)Pl + qrow*128 + swo);
#pragma unroll
            for (int m=0;m<4;++m){
                int off = (m*16+l15)*128 + swo;
                bf16x8 vvh = *(const bf16x8*)((const char*)Vh + off);
                bf16x8 vvl = *(const bf16x8*)((const char*)Vl + off);
                ot[m] = MFMA16(vvh, pfh, ot[m]);
                ot[m] = MFMA16(vvh, pfl, ot[m]);
                ot[m] = MFMA16(vvl, pfh, ot[m]);
            }
        }
    }
    __syncthreads();
    // normalize + transpose via LDS, write att split bf16
    float inv = 1.f/lrun;
#pragma unroll
    for (int m=0;m<4;++m)
#pragma unroll
        for (int j=0;j<4;++j){
            int d = m*16 + l4*4 + j;
            OT[qrow*68 + d] = ot[m][j]*inv;
        }
    __syncthreads();
    {
        int q = tid>>2, d0 = (tid&3)*16;
        const float* rp = OT + q*68 + d0;
        float4 f0=((const float4*)rp)[0], f1=((const float4*)rp)[1];
        float4 f2=((const float4*)rp)[2], f3=((const float4*)rp)[3];
        float f[16]={f0.x,f0.y,f0.z,f0.w,f1.x,f1.y,f1.z,f1.w,f2.x,f2.y,f2.z,f2.w,f3.x,f3.y,f3.z,f3.w};
        bf16x8 vh[2], vl[2];
#pragma unroll
        for (int g=0;g<2;++g)
#pragma unroll
            for (int e=0;e<8;++e){
                unsigned short hh = f2bf(f[g*8+e]);
                vh[g][e] = (short)hh;
                vl[g][e] = (short)f2bf(f[g*8+e]-bf2f(hh));
            }
        long o = base + (long)(q0+q)*E_ + d0;
        *(bf16x8*)(atth + o)     = vh[0];
        *(bf16x8*)(atth + o + 8) = vh[1];
        *(bf16x8*)(attl + o)     = vl[0];
        *(bf16x8*)(attl + o + 8) = vl[1];
    }
}

// ---------------------------------------------------------------------------
// output projection GEMM: (att_hi + att_lo) x Wo_hi (2 products; Wo_lo dropped
// — adds ~0.004 to I, ~0.005 to out, well under 0.02) + fresh-state spike
__global__ __launch_bounds__(256,2) void out_k(const unsigned short* __restrict__ Ah_g,
        const unsigned short* __restrict__ Al_g,
        const unsigned short* __restrict__ Wh,
        const float* __restrict__ bias, float* __restrict__ out){
    const int row0 = blockIdx.x*128, col0 = blockIdx.y*64;
    __shared__ unsigned short Ah[128*64], Al[128*64];
    __shared__ unsigned short Bh2[64*64];

    const int tid = threadIdx.x, lane = tid&63, wid = tid>>6;
    const int l15 = lane&15, l4 = lane>>4, l7 = lane&7;
    const int wr = wid>>1, wc = wid&1;

    int aSrc[4], bSrc[2];
#pragma unroll
    for (int s=0;s<4;++s){
        int idx = (wid + s*4)*64 + lane;
        int row = idx>>3, ch = idx&7;
        aSrc[s] = (row0+row)*E_ + ((ch ^ (row&7))<<3);
    }
#pragma unroll
    for (int s=0;s<2;++s){
        int idx = (wid + s*4)*64 + lane;
        int row = idx>>3, ch = idx&7;
        bSrc[s] = (col0+row)*E_ + ((ch ^ (row&7))<<3);
    }
    const int aBase = (wr*64 + l15)*128;
    const int bBase = (wc*32 + l15)*128;
    const int sw[2] = { ((l4^l7)<<4), ((((4+l4))^l7)<<4) };

    f32x4 acc[4][2];
    const f32x4 zero4 = {0.f,0.f,0.f,0.f};
#pragma unroll
    for (int m=0;m<4;++m)
#pragma unroll
        for (int n=0;n<2;++n) acc[m][n] = zero4;

    for (int kt=0;kt<12;++kt){
        const int k0 = kt*64;
        __syncthreads();
#pragma unroll
        for (int s=0;s<4;++s){
            gl16(Ah_g + aSrc[s] + k0, &Ah[(wid+s*4)*512]);
            gl16(Al_g + aSrc[s] + k0, &Al[(wid+s*4)*512]);
        }
#pragma unroll
        for (int s=0;s<2;++s)
            gl16(Wh + bSrc[s] + k0, &Bh2[(wid+s*4)*512]);
        __syncthreads();
#pragma unroll
        for (int kk=0;kk<2;++kk){
            bf16x8 ah[4], al[4], fbh[2];
#pragma unroll
            for (int m=0;m<4;++m){
                ah[m] = *(const bf16x8*)((const char*)Ah + aBase + m*2048 + sw[kk]);
                al[m] = *(const bf16x8*)((const char*)Al + aBase + m*2048 + sw[kk]);
            }
#pragma unroll
            for (int n=0;n<2;++n)
                fbh[n] = *(const bf16x8*)((const char*)Bh2 + bBase + n*2048 + sw[kk]);
#pragma unroll
            for (int m=0;m<4;++m)
#pragma unroll
                for (int n=0;n<2;++n){
                    acc[m][n] = MFMA16(ah[m], fbh[n], acc[m][n]);
                    acc[m][n] = MFMA16(al[m], fbh[n], acc[m][n]);
                }
        }
    }
#pragma unroll
    for (int m=0;m<4;++m)
#pragma unroll
        for (int n=0;n<2;++n){
            float bn = bias[col0 + wc*32 + n*16 + l15];
#pragma unroll
            for (int j=0;j<4;++j){
                int row = row0 + wr*64 + m*16 + l4*4 + j;
                int col = col0 + wc*32 + n*16 + l15;
                float I = acc[m][n][j] + bn;
                out[(long)row*E_ + col] = sigm(5.f*I - 10.f);   // lif_step(0, I) spike
            }
        }
}

// ---------------------------------------------------------------------------
extern "C" void kernel_launch(void* const* d_in, const int* in_sizes, int n_in,
                              void* d_out, int out_size, void* d_ws, size_t ws_size,
                              hipStream_t stream){
    const float* x  = (const float*)d_in[0];
    const float* Wq = (const float*)d_in[1];
    const float* bq = (const float*)d_in[2];
    const float* Wk = (const float*)d_in[3];
    const float* bk = (const float*)d_in[4];
    const float* Wv = (const float*)d_in[5];
    const float* bv = (const float*)d_in[6];
    const float* Wo = (const float*)d_in[7];
    const float* bo = (const float*)d_in[8];
    float* out = (float*)d_out;

    // ws layout (~201 MiB):
    //  [0, 125829120)            enc bf16 [10][N][E]   (dead after qkv_k; att reuses)
    //  [125829120, 135266304)    whi/wlo bf16 [4][E*E]
    //  [135266304, 210763776)    Qf/Kf/Vf fp32 [N][E]
    char* ws = (char*)d_ws;
    unsigned short* enc  = (unsigned short*)ws;
    unsigned short* atth = (unsigned short*)ws;
    unsigned short* attl = (unsigned short*)(ws + (long)NE_*2);
    unsigned short* whi  = (unsigned short*)(ws + 125829120L);
    unsigned short* wlo  = whi + 4L*WE_;
    float* Qf = (float*)(ws + 135266304L);
    float* Kf = Qf + NE_;
    float* Vf = Kf + NE_;

    wsplit_k<<<dim3(4*(WE_/8)/256), 256, 0, stream>>>(Wq,Wk,Wv,Wo,whi,wlo);
    encode_k<<<dim3(NE_/8/256), 256, 0, stream>>>(x,enc);
    qkv_k<<<dim3(64,12,3), 256, 0, stream>>>(enc,whi,bq,bk,bv,Qf,Kf,Vf);
    attn_k2<<<dim3(16,12,8), 256, 0, stream>>>(Qf,Kf,Vf,atth,attl);
    out_k<<<dim3(64,12), 256, 0, stream>>>(atth,attl,whi+3L*WE_,bo,out);
}